// Round 10
// baseline (182.047 us; speedup 1.0000x reference)
//
#include <hip/hip_runtime.h>
#include <hip/hip_bf16.h>
#include <math.h>

// Problem constants (B,C,H,W)=(4,128,64,64), NUM_HEADS=4
#define BB 4
#define CC 128
#define NH 4
#define DH 32
#define NN 4096
#define OC3 (3*CC)

typedef __attribute__((ext_vector_type(8))) short short8;   // 8 bf16 MFMA A/B frag
typedef __attribute__((ext_vector_type(4))) short short4v;
typedef __attribute__((ext_vector_type(4))) float float4v;  // MFMA C/D frag

__device__ inline short f2bf(float f) {     // RNE bf16 (scalar path)
    unsigned u = __builtin_bit_cast(unsigned, f);
    u += 0x7FFF + ((u >> 16) & 1);
    return (short)(u >> 16);
}
__device__ inline unsigned pk2bf(float a, float b) {  // low=bf16(a), high=bf16(b)
    __hip_bfloat162 h = __float22bfloat162_rn(make_float2(a, b));
    unsigned u; __builtin_memcpy(&u, &h, 4);
    return u;
}

// ---------------------------------------------------------------------------
// Kernel 1: fused LayerNorm + QKV MFMA conv (R7 version — best measured).
// 512 thr = 8 waves; grid 256: one block per 64-n tile; LN once, then all 24
// o-tiles (wave w does o-tiles w, w+8, w+16 -> it=0:Q, 1:K, 2:V uniformly).
// qT/kT: [bh][n][c] bf16. v: [bh][c][m] bf16.
// ---------------------------------------------------------------------------
#define HS 136
__global__ __launch_bounds__(512, 4) void lnqkv_kernel(
        const float* __restrict__ x, const float* __restrict__ nw,
        const float* __restrict__ nb, const float* __restrict__ qw,
        const float* __restrict__ qbias,
        short* __restrict__ qT, short* __restrict__ kT, short* __restrict__ vv) {
    __shared__ short hT[64 * HS];
    __shared__ float red[16][64];
    __shared__ float mrs[2][64];
    int t = threadIdx.x;
    int n0g = blockIdx.x * 64;
    int b = n0g >> 12, n0 = n0g & (NN - 1);
    int nl = t & 63, cq = t >> 6;          // cq 0..7, owns 16 channels

    const float* xp = x + ((size_t)b * CC + cq * 16) * NN + n0 + nl;
    float xv[16];
    float s = 0.f, ss = 0.f;
    #pragma unroll
    for (int j = 0; j < 16; ++j) {
        xv[j] = xp[(size_t)j * NN];
        s += xv[j]; ss += xv[j] * xv[j];
    }
    red[cq][nl] = s; red[cq + 8][nl] = ss;
    __syncthreads();
    if (t < 64) {
        float s8 = 0.f, q8 = 0.f;
        #pragma unroll
        for (int j = 0; j < 8; ++j) { s8 += red[j][t]; q8 += red[j + 8][t]; }
        float mean = s8 * (1.0f / CC);
        float var  = q8 * (1.0f / CC) - mean * mean;
        mrs[0][t] = mean;
        mrs[1][t] = rsqrtf(var + 1e-6f);
    }
    __syncthreads();
    {
        float mean = mrs[0][nl], rsv = mrs[1][nl];
        #pragma unroll
        for (int j = 0; j < 16; j += 8) {
            union { short8 v; unsigned u[4]; } z;
            #pragma unroll
            for (int k = 0; k < 4; ++k) {
                int c = cq * 16 + j + 2 * k;
                float h0 = (xv[j + 2 * k]     - mean) * rsv * nw[c]     + nb[c];
                float h1 = (xv[j + 2 * k + 1] - mean) * rsv * nw[c + 1] + nb[c + 1];
                z.u[k] = pk2bf(h0, h1);
            }
            *(short8*)&hT[nl * HS + cq * 16 + j] = z.v;
        }
    }
    __syncthreads();

    int w = t >> 6, lane = t & 63;
    int lg = lane >> 4, ln = lane & 15;
    #pragma unroll
    for (int it = 0; it < 3; ++it) {
        int ow = (w + it * 8) * 16;
        const float* wp = qw + (size_t)(ow + ln) * CC;
        float4v a0 = {0,0,0,0}, a1 = {0,0,0,0}, a2 = {0,0,0,0}, a3 = {0,0,0,0};
        #pragma unroll
        for (int cs = 0; cs < 4; ++cs) {
            float4 wa = *(const float4*)(wp + cs * 32 + lg * 8);
            float4 wb = *(const float4*)(wp + cs * 32 + lg * 8 + 4);
            union { short8 v; unsigned u[4]; } af;
            af.u[0] = pk2bf(wa.x, wa.y); af.u[1] = pk2bf(wa.z, wa.w);
            af.u[2] = pk2bf(wb.x, wb.y); af.u[3] = pk2bf(wb.z, wb.w);
            const short* hp = &hT[cs * 32 + lg * 8];
            a0 = __builtin_amdgcn_mfma_f32_16x16x32_bf16(af.v, *(const short8*)&hp[(0  + ln) * HS], a0, 0, 0, 0);
            a1 = __builtin_amdgcn_mfma_f32_16x16x32_bf16(af.v, *(const short8*)&hp[(16 + ln) * HS], a1, 0, 0, 0);
            a2 = __builtin_amdgcn_mfma_f32_16x16x32_bf16(af.v, *(const short8*)&hp[(32 + ln) * HS], a2, 0, 0, 0);
            a3 = __builtin_amdgcn_mfma_f32_16x16x32_bf16(af.v, *(const short8*)&hp[(48 + ln) * HS], a3, 0, 0, 0);
        }
        int r0 = ow + lg * 4;
        float b0 = qbias[r0], b1 = qbias[r0 + 1], b2 = qbias[r0 + 2], b3 = qbias[r0 + 3];
        int cb = ow & 31;
        float4v* accs[4] = {&a0, &a1, &a2, &a3};
        if (it == 0) {            // Q: scaled by scale*log2e
            const float qs = 0.1767766952966369f * 1.4426950408889634f;
            int hh = ow >> 5;
            size_t rowbase = (size_t)(b * NH + hh) * NN + n0;
            #pragma unroll
            for (int nsub = 0; nsub < 4; ++nsub) {
                float4v av = *accs[nsub];
                union { short4v v; unsigned u[2]; } z;
                z.u[0] = pk2bf((av.x + b0) * qs, (av.y + b1) * qs);
                z.u[1] = pk2bf((av.z + b2) * qs, (av.w + b3) * qs);
                *(short4v*)&qT[(rowbase + nsub * 16 + ln) * DH + cb + lg * 4] = z.v;
            }
        } else if (it == 1) {     // K
            int hh = (ow - CC) >> 5;
            size_t rowbase = (size_t)(b * NH + hh) * NN + n0;
            #pragma unroll
            for (int nsub = 0; nsub < 4; ++nsub) {
                float4v av = *accs[nsub];
                union { short4v v; unsigned u[2]; } z;
                z.u[0] = pk2bf(av.x + b0, av.y + b1);
                z.u[1] = pk2bf(av.z + b2, av.w + b3);
                *(short4v*)&kT[(rowbase + nsub * 16 + ln) * DH + cb + lg * 4] = z.v;
            }
        } else {                  // V: [bh][c][m]
            int hh = (ow - 2 * CC) >> 5;
            size_t cbase = (size_t)((b * NH + hh) * DH + cb + lg * 4);
            #pragma unroll
            for (int nsub = 0; nsub < 4; ++nsub) {
                float4v av = *accs[nsub];
                size_t col = (size_t)n0 + nsub * 16 + ln;
                vv[(cbase + 0) * NN + col] = f2bf(av.x + b0);
                vv[(cbase + 1) * NN + col] = f2bf(av.y + b1);
                vv[(cbase + 2) * NN + col] = f2bf(av.z + b2);
                vv[(cbase + 3) * NN + col] = f2bf(av.w + b3);
            }
        }
    }
}

// ---------------------------------------------------------------------------
// Kernel 2: MFMA flash attention v6. Unshifted-exp softmax (p = 2^s; bounded
// scores, constant cancels in normalization). Each wave: 64 queries
// (4 q-tiles) x 1024 keys (4-way split) = 16 steps of 64 keys. K/V frag
// loads (8/step) shared by all 4 q-tiles (4x reuse), but tiles processed
// FULLY SEQUENTIALLY (QK -> softmax -> PV per tile, single per-wave P-buf)
// to keep live registers < 128 -> no scratch spill (R9's failure mode).
// Same-wave in-order DS queue makes the P-buf reuse safe. 4-way split
// partials merged through LDS (aliased). Grid 512 blocks x 8 waves.
// ---------------------------------------------------------------------------
#define PS 72
union __align__(16) FlashSh {
    short pt[8 * 16 * PS];                       // 1 P-buf per wave (18432 B)
    struct { float mo[3][8][64][8]; float ml[3][8][64]; } m;  // 55296 B
};
__global__ __launch_bounds__(512, 4) void flash_kernel(
        const short* __restrict__ qT, const short* __restrict__ kT,
        const short* __restrict__ vv, short* __restrict__ aoT) {
    __shared__ FlashSh sh;
    int blk = blockIdx.x;
    int bh = blk >> 5;
    int qb = blk & 31;
    int b = bh >> 2, hh = bh & 3;
    int n0 = qb * 128;
    int t = threadIdx.x, w = t >> 6, lane = t & 63;
    int lg = lane >> 4, ln = lane & 15;
    int qg = w & 1;               // which 64-query group of the block's 128
    int split = w >> 1;           // key split 0..3

    const short* kbase = kT + (size_t)bh * NN * DH + lg * 8;
    const short* vb0 = vv + ((size_t)bh * DH + ln) * NN + lg * 8;
    const short* vb1 = vb0 + (size_t)16 * NN;

    short8 qf[4];
    #pragma unroll
    for (int j = 0; j < 4; ++j)
        qf[j] = *(const short8*)&qT[((size_t)bh * NN + n0 + (qg * 4 + j) * 16 + ln) * DH + lg * 8];

    float4v o0[4], o1[4];
    float ls[4];
    #pragma unroll
    for (int j = 0; j < 4; ++j) {
        o0[j] = (float4v){0,0,0,0}; o1[j] = (float4v){0,0,0,0}; ls[j] = 0.f;
    }
    short* ptw = &sh.pt[w * 16 * PS];

    int mbeg = split * (NN / 4), mend = mbeg + NN / 4;
    for (int m0 = mbeg; m0 < mend; m0 += 64) {
        // ---- shared loads: K frags (1KB/instr coalesced), V frags ----
        const short* kp = kbase + (size_t)m0 * DH;
        short8 k0 = *(const short8*)(kp + (size_t)(ln +  0) * DH);
        short8 k1 = *(const short8*)(kp + (size_t)(ln + 16) * DH);
        short8 k2 = *(const short8*)(kp + (size_t)(ln + 32) * DH);
        short8 k3 = *(const short8*)(kp + (size_t)(ln + 48) * DH);
        short8 v0 = *(const short8*)(vb0 + m0);
        short8 v1 = *(const short8*)(vb0 + m0 + 32);
        short8 v2 = *(const short8*)(vb1 + m0);
        short8 v3 = *(const short8*)(vb1 + m0 + 32);

        // ---- per q-tile: QK -> softmax -> pack -> PV (one P-buf, reused;
        //      in-order same-wave DS queue keeps write_j/read_j correct) ----
        #pragma unroll
        for (int j = 0; j < 4; ++j) {
            float4v s0 = {0,0,0,0}, s1 = s0, s2 = s0, s3 = s0;
            s0 = __builtin_amdgcn_mfma_f32_16x16x32_bf16(k0, qf[j], s0, 0, 0, 0);
            s1 = __builtin_amdgcn_mfma_f32_16x16x32_bf16(k1, qf[j], s1, 0, 0, 0);
            s2 = __builtin_amdgcn_mfma_f32_16x16x32_bf16(k2, qf[j], s2, 0, 0, 0);
            s3 = __builtin_amdgcn_mfma_f32_16x16x32_bf16(k3, qf[j], s3, 0, 0, 0);
            float lacc = 0.f;
            float4v* sv[4] = {&s0, &s1, &s2, &s3};
            #pragma unroll
            for (int jj = 0; jj < 4; ++jj) {
                float4v sj = *sv[jj];
                float p0 = __builtin_amdgcn_exp2f(sj.x);
                float p1 = __builtin_amdgcn_exp2f(sj.y);
                float p2 = __builtin_amdgcn_exp2f(sj.z);
                float p3 = __builtin_amdgcn_exp2f(sj.w);
                lacc += (p0 + p1) + (p2 + p3);
                union { short4v v; unsigned u[2]; } z;
                z.u[0] = pk2bf(p0, p1); z.u[1] = pk2bf(p2, p3);
                *(short4v*)&ptw[ln * PS + jj * 16 + lg * 4] = z.v;
            }
            ls[j] += lacc;
            short8 pb0 = *(const short8*)&ptw[ln * PS + 0  + lg * 8];
            short8 pb1 = *(const short8*)&ptw[ln * PS + 32 + lg * 8];
            o0[j] = __builtin_amdgcn_mfma_f32_16x16x32_bf16(v0, pb0, o0[j], 0, 0, 0);
            o1[j] = __builtin_amdgcn_mfma_f32_16x16x32_bf16(v2, pb0, o1[j], 0, 0, 0);
            o0[j] = __builtin_amdgcn_mfma_f32_16x16x32_bf16(v1, pb1, o0[j], 0, 0, 0);
            o1[j] = __builtin_amdgcn_mfma_f32_16x16x32_bf16(v3, pb1, o1[j], 0, 0, 0);
        }
    }

    // ---- all waves done with pt before aliasing it as merge buffers ----
    __syncthreads();
    if (split > 0) {
        int si = split - 1;
        #pragma unroll
        for (int j = 0; j < 4; ++j) {
            int tid = qg * 4 + j;
            float* mp = &sh.m.mo[si][tid][lane][0];
            *(float4*)(mp + 0) = make_float4(o0[j].x, o0[j].y, o0[j].z, o0[j].w);
            *(float4*)(mp + 4) = make_float4(o1[j].x, o1[j].y, o1[j].z, o1[j].w);
            sh.m.ml[si][tid][lane] = ls[j];
        }
    }
    __syncthreads();
    if (split == 0) {
        #pragma unroll
        for (int j = 0; j < 4; ++j) {
            int tid = qg * 4 + j;
            #pragma unroll
            for (int si = 0; si < 3; ++si) {
                const float* mp = &sh.m.mo[si][tid][lane][0];
                float4 a0 = *(const float4*)(mp + 0);
                float4 a1 = *(const float4*)(mp + 4);
                o0[j].x += a0.x; o0[j].y += a0.y; o0[j].z += a0.z; o0[j].w += a0.w;
                o1[j].x += a1.x; o1[j].y += a1.y; o1[j].z += a1.z; o1[j].w += a1.w;
                ls[j] += sh.m.ml[si][tid][lane];
            }
            float lt = ls[j];
            lt += __shfl_xor(lt, 16, 64);
            lt += __shfl_xor(lt, 32, 64);
            float inv = 1.0f / lt;
            short* ap = aoT + ((size_t)b * NN + n0 + tid * 16 + ln) * CC + hh * DH;
            union { short4v v; unsigned u[2]; } z;
            z.u[0] = pk2bf(o0[j].x * inv, o0[j].y * inv);
            z.u[1] = pk2bf(o0[j].z * inv, o0[j].w * inv);
            *(short4v*)&ap[lg * 4] = z.v;
            z.u[0] = pk2bf(o1[j].x * inv, o1[j].y * inv);
            z.u[1] = pk2bf(o1[j].z * inv, o1[j].w * inv);
            *(short4v*)&ap[16 + lg * 4] = z.v;
        }
    }
}

// ---------------------------------------------------------------------------
// Kernel 3: proj MFMA conv + bias + residual (fp32 out). B-frags direct from
// global ao^T bf16; no LDS. Block 4 waves = 64o x 64n; grid (256, 2).
// ---------------------------------------------------------------------------
__global__ __launch_bounds__(256) void proj_kernel(
        const short* __restrict__ aoT, const float* __restrict__ pw,
        const float* __restrict__ pb, const float* __restrict__ x,
        float* __restrict__ out) {
    int t = threadIdx.x;
    int n0g = blockIdx.x * 64;
    int b = n0g >> 12, n0 = n0g & (NN - 1);
    int o0 = blockIdx.y * 64;
    int wo = t >> 6, lane = t & 63;
    int lg = lane >> 4, ln = lane & 15;
    int ow = o0 + wo * 16;
    const float* wp = pw + (size_t)(ow + ln) * CC;
    const short* ap = aoT + (size_t)n0g * CC + lg * 8;
    float4v a0 = {0,0,0,0}, a1 = {0,0,0,0}, a2 = {0,0,0,0}, a3 = {0,0,0,0};
    #pragma unroll
    for (int cs = 0; cs < 4; ++cs) {
        float4 wa = *(const float4*)(wp + cs * 32 + lg * 8);
        float4 wb = *(const float4*)(wp + cs * 32 + lg * 8 + 4);
        union { short8 v; unsigned u[4]; } af;
        af.u[0] = pk2bf(wa.x, wa.y); af.u[1] = pk2bf(wa.z, wa.w);
        af.u[2] = pk2bf(wb.x, wb.y); af.u[3] = pk2bf(wb.z, wb.w);
        const short* hp = ap + cs * 32;
        a0 = __builtin_amdgcn_mfma_f32_16x16x32_bf16(af.v, *(const short8*)&hp[(size_t)(0  + ln) * CC], a0, 0, 0, 0);
        a1 = __builtin_amdgcn_mfma_f32_16x16x32_bf16(af.v, *(const short8*)&hp[(size_t)(16 + ln) * CC], a1, 0, 0, 0);
        a2 = __builtin_amdgcn_mfma_f32_16x16x32_bf16(af.v, *(const short8*)&hp[(size_t)(32 + ln) * CC], a2, 0, 0, 0);
        a3 = __builtin_amdgcn_mfma_f32_16x16x32_bf16(af.v, *(const short8*)&hp[(size_t)(48 + ln) * CC], a3, 0, 0, 0);
    }
    int r0 = ow + lg * 4;
    float b0 = pb[r0], b1 = pb[r0 + 1], b2 = pb[r0 + 2], b3 = pb[r0 + 3];
    const float* xbase = x   + ((size_t)b * CC + r0) * NN + n0 + ln;
    float*       obase = out + ((size_t)b * CC + r0) * NN + n0 + ln;
    float4v* accs[4] = {&a0, &a1, &a2, &a3};
    #pragma unroll
    for (int nsub = 0; nsub < 4; ++nsub) {
        float4v av = *accs[nsub];
        const float* xp = xbase + nsub * 16;
        float* op = obase + nsub * 16;
        op[(size_t)0 * NN] = av.x + b0 + xp[(size_t)0 * NN];
        op[(size_t)1 * NN] = av.y + b1 + xp[(size_t)1 * NN];
        op[(size_t)2 * NN] = av.z + b2 + xp[(size_t)2 * NN];
        op[(size_t)3 * NN] = av.w + b3 + xp[(size_t)3 * NN];
    }
}

// ---------------------------------------------------------------------------
extern "C" void kernel_launch(void* const* d_in, const int* in_sizes, int n_in,
                              void* d_out, int out_size, void* d_ws, size_t ws_size,
                              hipStream_t stream) {
    const float* x    = (const float*)d_in[0];
    const float* nw   = (const float*)d_in[1];
    const float* nb   = (const float*)d_in[2];
    const float* qkvw = (const float*)d_in[3];
    const float* qkvb = (const float*)d_in[4];
    const float* pw   = (const float*)d_in[5];
    const float* pb   = (const float*)d_in[6];
    float* out = (float*)d_out;

    // ws (shorts): qT | kT | v | aoT  (4 MB each, 16 MB total)
    short* qT  = (short*)d_ws;
    short* kT  = qT + (size_t)BB * NH * NN * DH;
    short* vv  = kT + (size_t)BB * NH * NN * DH;
    short* aoT = vv + (size_t)BB * NH * DH * NN;

    lnqkv_kernel<<<dim3(256), 512, 0, stream>>>(x, nw, nb, qkvw, qkvb, qT, kT, vv);
    flash_kernel<<<dim3(512), 512, 0, stream>>>(qT, kT, vv, aoT);
    proj_kernel<<<dim3(256, 2), 256, 0, stream>>>(aoT, pw, pb, x, out);
}

// Round 11
// 144.524 us; speedup vs baseline: 1.2596x; 1.2596x over previous
//
#include <hip/hip_runtime.h>
#include <hip/hip_bf16.h>
#include <math.h>

// Problem constants (B,C,H,W)=(4,128,64,64), NUM_HEADS=4
#define BB 4
#define CC 128
#define NH 4
#define DH 32
#define NN 4096
#define OC3 (3*CC)

typedef __attribute__((ext_vector_type(8))) short short8;   // 8 bf16 MFMA A/B frag
typedef __attribute__((ext_vector_type(4))) short short4v;
typedef __attribute__((ext_vector_type(4))) float float4v;  // MFMA C/D frag

__device__ inline short f2bf(float f) {     // RNE bf16 (scalar path)
    unsigned u = __builtin_bit_cast(unsigned, f);
    u += 0x7FFF + ((u >> 16) & 1);
    return (short)(u >> 16);
}
__device__ inline unsigned pk2bf(float a, float b) {  // low=bf16(a), high=bf16(b)
    __hip_bfloat162 h = __float22bfloat162_rn(make_float2(a, b));
    unsigned u; __builtin_memcpy(&u, &h, 4);
    return u;
}

// ---------------------------------------------------------------------------
// Kernel 1: fused LayerNorm + QKV MFMA conv (R7 version — best measured).
// ---------------------------------------------------------------------------
#define HS 136
__global__ __launch_bounds__(512, 4) void lnqkv_kernel(
        const float* __restrict__ x, const float* __restrict__ nw,
        const float* __restrict__ nb, const float* __restrict__ qw,
        const float* __restrict__ qbias,
        short* __restrict__ qT, short* __restrict__ kT, short* __restrict__ vv) {
    __shared__ short hT[64 * HS];
    __shared__ float red[16][64];
    __shared__ float mrs[2][64];
    int t = threadIdx.x;
    int n0g = blockIdx.x * 64;
    int b = n0g >> 12, n0 = n0g & (NN - 1);
    int nl = t & 63, cq = t >> 6;          // cq 0..7, owns 16 channels

    const float* xp = x + ((size_t)b * CC + cq * 16) * NN + n0 + nl;
    float xv[16];
    float s = 0.f, ss = 0.f;
    #pragma unroll
    for (int j = 0; j < 16; ++j) {
        xv[j] = xp[(size_t)j * NN];
        s += xv[j]; ss += xv[j] * xv[j];
    }
    red[cq][nl] = s; red[cq + 8][nl] = ss;
    __syncthreads();
    if (t < 64) {
        float s8 = 0.f, q8 = 0.f;
        #pragma unroll
        for (int j = 0; j < 8; ++j) { s8 += red[j][t]; q8 += red[j + 8][t]; }
        float mean = s8 * (1.0f / CC);
        float var  = q8 * (1.0f / CC) - mean * mean;
        mrs[0][t] = mean;
        mrs[1][t] = rsqrtf(var + 1e-6f);
    }
    __syncthreads();
    {
        float mean = mrs[0][nl], rsv = mrs[1][nl];
        #pragma unroll
        for (int j = 0; j < 16; j += 8) {
            union { short8 v; unsigned u[4]; } z;
            #pragma unroll
            for (int k = 0; k < 4; ++k) {
                int c = cq * 16 + j + 2 * k;
                float h0 = (xv[j + 2 * k]     - mean) * rsv * nw[c]     + nb[c];
                float h1 = (xv[j + 2 * k + 1] - mean) * rsv * nw[c + 1] + nb[c + 1];
                z.u[k] = pk2bf(h0, h1);
            }
            *(short8*)&hT[nl * HS + cq * 16 + j] = z.v;
        }
    }
    __syncthreads();

    int w = t >> 6, lane = t & 63;
    int lg = lane >> 4, ln = lane & 15;
    #pragma unroll
    for (int it = 0; it < 3; ++it) {
        int ow = (w + it * 8) * 16;
        const float* wp = qw + (size_t)(ow + ln) * CC;
        float4v a0 = {0,0,0,0}, a1 = {0,0,0,0}, a2 = {0,0,0,0}, a3 = {0,0,0,0};
        #pragma unroll
        for (int cs = 0; cs < 4; ++cs) {
            float4 wa = *(const float4*)(wp + cs * 32 + lg * 8);
            float4 wb = *(const float4*)(wp + cs * 32 + lg * 8 + 4);
            union { short8 v; unsigned u[4]; } af;
            af.u[0] = pk2bf(wa.x, wa.y); af.u[1] = pk2bf(wa.z, wa.w);
            af.u[2] = pk2bf(wb.x, wb.y); af.u[3] = pk2bf(wb.z, wb.w);
            const short* hp = &hT[cs * 32 + lg * 8];
            a0 = __builtin_amdgcn_mfma_f32_16x16x32_bf16(af.v, *(const short8*)&hp[(0  + ln) * HS], a0, 0, 0, 0);
            a1 = __builtin_amdgcn_mfma_f32_16x16x32_bf16(af.v, *(const short8*)&hp[(16 + ln) * HS], a1, 0, 0, 0);
            a2 = __builtin_amdgcn_mfma_f32_16x16x32_bf16(af.v, *(const short8*)&hp[(32 + ln) * HS], a2, 0, 0, 0);
            a3 = __builtin_amdgcn_mfma_f32_16x16x32_bf16(af.v, *(const short8*)&hp[(48 + ln) * HS], a3, 0, 0, 0);
        }
        int r0 = ow + lg * 4;
        float b0 = qbias[r0], b1 = qbias[r0 + 1], b2 = qbias[r0 + 2], b3 = qbias[r0 + 3];
        int cb = ow & 31;
        float4v* accs[4] = {&a0, &a1, &a2, &a3};
        if (it == 0) {            // Q: scaled by scale*log2e
            const float qs = 0.1767766952966369f * 1.4426950408889634f;
            int hh = ow >> 5;
            size_t rowbase = (size_t)(b * NH + hh) * NN + n0;
            #pragma unroll
            for (int nsub = 0; nsub < 4; ++nsub) {
                float4v av = *accs[nsub];
                union { short4v v; unsigned u[2]; } z;
                z.u[0] = pk2bf((av.x + b0) * qs, (av.y + b1) * qs);
                z.u[1] = pk2bf((av.z + b2) * qs, (av.w + b3) * qs);
                *(short4v*)&qT[(rowbase + nsub * 16 + ln) * DH + cb + lg * 4] = z.v;
            }
        } else if (it == 1) {     // K
            int hh = (ow - CC) >> 5;
            size_t rowbase = (size_t)(b * NH + hh) * NN + n0;
            #pragma unroll
            for (int nsub = 0; nsub < 4; ++nsub) {
                float4v av = *accs[nsub];
                union { short4v v; unsigned u[2]; } z;
                z.u[0] = pk2bf(av.x + b0, av.y + b1);
                z.u[1] = pk2bf(av.z + b2, av.w + b3);
                *(short4v*)&kT[(rowbase + nsub * 16 + ln) * DH + cb + lg * 4] = z.v;
            }
        } else {                  // V: [bh][c][m]
            int hh = (ow - 2 * CC) >> 5;
            size_t cbase = (size_t)((b * NH + hh) * DH + cb + lg * 4);
            #pragma unroll
            for (int nsub = 0; nsub < 4; ++nsub) {
                float4v av = *accs[nsub];
                size_t col = (size_t)n0 + nsub * 16 + ln;
                vv[(cbase + 0) * NN + col] = f2bf(av.x + b0);
                vv[(cbase + 1) * NN + col] = f2bf(av.y + b1);
                vv[(cbase + 2) * NN + col] = f2bf(av.z + b2);
                vv[(cbase + 3) * NN + col] = f2bf(av.w + b3);
            }
        }
    }
}

// ---------------------------------------------------------------------------
// Kernel 2: MFMA flash attention v7 == v6 structure, but launch bounds relaxed
// to (512, 2): R9/R10 showed (512,4) caps the allocator at 64 VGPR (4 blocks/
// CU x 8 waves = 32 waves/CU) and forces ~36 KB/wave scratch spill
// (WRITE_SIZE 158 MB). At 2 blocks/CU the cap is 128 VGPR; live set ~100-110
// fits with zero spill. Everything else identical to R10.
// ---------------------------------------------------------------------------
#define PS 72
union __align__(16) FlashSh {
    short pt[8 * 16 * PS];                       // 1 P-buf per wave (18432 B)
    struct { float mo[3][8][64][8]; float ml[3][8][64]; } m;  // 55296 B
};
__global__ __launch_bounds__(512, 2) void flash_kernel(
        const short* __restrict__ qT, const short* __restrict__ kT,
        const short* __restrict__ vv, short* __restrict__ aoT) {
    __shared__ FlashSh sh;
    int blk = blockIdx.x;
    int bh = blk >> 5;
    int qb = blk & 31;
    int b = bh >> 2, hh = bh & 3;
    int n0 = qb * 128;
    int t = threadIdx.x, w = t >> 6, lane = t & 63;
    int lg = lane >> 4, ln = lane & 15;
    int qg = w & 1;               // which 64-query group of the block's 128
    int split = w >> 1;           // key split 0..3

    const short* kbase = kT + (size_t)bh * NN * DH + lg * 8;
    const short* vb0 = vv + ((size_t)bh * DH + ln) * NN + lg * 8;
    const short* vb1 = vb0 + (size_t)16 * NN;

    short8 qf[4];
    #pragma unroll
    for (int j = 0; j < 4; ++j)
        qf[j] = *(const short8*)&qT[((size_t)bh * NN + n0 + (qg * 4 + j) * 16 + ln) * DH + lg * 8];

    float4v o0[4], o1[4];
    float ls[4];
    #pragma unroll
    for (int j = 0; j < 4; ++j) {
        o0[j] = (float4v){0,0,0,0}; o1[j] = (float4v){0,0,0,0}; ls[j] = 0.f;
    }
    short* ptw = &sh.pt[w * 16 * PS];

    int mbeg = split * (NN / 4), mend = mbeg + NN / 4;
    for (int m0 = mbeg; m0 < mend; m0 += 64) {
        // ---- shared loads: K frags (1KB/instr coalesced), V frags ----
        const short* kp = kbase + (size_t)m0 * DH;
        short8 k0 = *(const short8*)(kp + (size_t)(ln +  0) * DH);
        short8 k1 = *(const short8*)(kp + (size_t)(ln + 16) * DH);
        short8 k2 = *(const short8*)(kp + (size_t)(ln + 32) * DH);
        short8 k3 = *(const short8*)(kp + (size_t)(ln + 48) * DH);
        short8 v0 = *(const short8*)(vb0 + m0);
        short8 v1 = *(const short8*)(vb0 + m0 + 32);
        short8 v2 = *(const short8*)(vb1 + m0);
        short8 v3 = *(const short8*)(vb1 + m0 + 32);

        // ---- per q-tile: QK -> softmax -> pack -> PV (one P-buf, reused;
        //      in-order same-wave DS queue keeps write_j/read_j correct) ----
        #pragma unroll
        for (int j = 0; j < 4; ++j) {
            float4v s0 = {0,0,0,0}, s1 = s0, s2 = s0, s3 = s0;
            s0 = __builtin_amdgcn_mfma_f32_16x16x32_bf16(k0, qf[j], s0, 0, 0, 0);
            s1 = __builtin_amdgcn_mfma_f32_16x16x32_bf16(k1, qf[j], s1, 0, 0, 0);
            s2 = __builtin_amdgcn_mfma_f32_16x16x32_bf16(k2, qf[j], s2, 0, 0, 0);
            s3 = __builtin_amdgcn_mfma_f32_16x16x32_bf16(k3, qf[j], s3, 0, 0, 0);
            float lacc = 0.f;
            float4v* sv[4] = {&s0, &s1, &s2, &s3};
            #pragma unroll
            for (int jj = 0; jj < 4; ++jj) {
                float4v sj = *sv[jj];
                float p0 = __builtin_amdgcn_exp2f(sj.x);
                float p1 = __builtin_amdgcn_exp2f(sj.y);
                float p2 = __builtin_amdgcn_exp2f(sj.z);
                float p3 = __builtin_amdgcn_exp2f(sj.w);
                lacc += (p0 + p1) + (p2 + p3);
                union { short4v v; unsigned u[2]; } z;
                z.u[0] = pk2bf(p0, p1); z.u[1] = pk2bf(p2, p3);
                *(short4v*)&ptw[ln * PS + jj * 16 + lg * 4] = z.v;
            }
            ls[j] += lacc;
            short8 pb0 = *(const short8*)&ptw[ln * PS + 0  + lg * 8];
            short8 pb1 = *(const short8*)&ptw[ln * PS + 32 + lg * 8];
            o0[j] = __builtin_amdgcn_mfma_f32_16x16x32_bf16(v0, pb0, o0[j], 0, 0, 0);
            o1[j] = __builtin_amdgcn_mfma_f32_16x16x32_bf16(v2, pb0, o1[j], 0, 0, 0);
            o0[j] = __builtin_amdgcn_mfma_f32_16x16x32_bf16(v1, pb1, o0[j], 0, 0, 0);
            o1[j] = __builtin_amdgcn_mfma_f32_16x16x32_bf16(v3, pb1, o1[j], 0, 0, 0);
        }
    }

    // ---- all waves done with pt before aliasing it as merge buffers ----
    __syncthreads();
    if (split > 0) {
        int si = split - 1;
        #pragma unroll
        for (int j = 0; j < 4; ++j) {
            int tid = qg * 4 + j;
            float* mp = &sh.m.mo[si][tid][lane][0];
            *(float4*)(mp + 0) = make_float4(o0[j].x, o0[j].y, o0[j].z, o0[j].w);
            *(float4*)(mp + 4) = make_float4(o1[j].x, o1[j].y, o1[j].z, o1[j].w);
            sh.m.ml[si][tid][lane] = ls[j];
        }
    }
    __syncthreads();
    if (split == 0) {
        #pragma unroll
        for (int j = 0; j < 4; ++j) {
            int tid = qg * 4 + j;
            #pragma unroll
            for (int si = 0; si < 3; ++si) {
                const float* mp = &sh.m.mo[si][tid][lane][0];
                float4 a0 = *(const float4*)(mp + 0);
                float4 a1 = *(const float4*)(mp + 4);
                o0[j].x += a0.x; o0[j].y += a0.y; o0[j].z += a0.z; o0[j].w += a0.w;
                o1[j].x += a1.x; o1[j].y += a1.y; o1[j].z += a1.z; o1[j].w += a1.w;
                ls[j] += sh.m.ml[si][tid][lane];
            }
            float lt = ls[j];
            lt += __shfl_xor(lt, 16, 64);
            lt += __shfl_xor(lt, 32, 64);
            float inv = 1.0f / lt;
            short* ap = aoT + ((size_t)b * NN + n0 + tid * 16 + ln) * CC + hh * DH;
            union { short4v v; unsigned u[2]; } z;
            z.u[0] = pk2bf(o0[j].x * inv, o0[j].y * inv);
            z.u[1] = pk2bf(o0[j].z * inv, o0[j].w * inv);
            *(short4v*)&ap[lg * 4] = z.v;
            z.u[0] = pk2bf(o1[j].x * inv, o1[j].y * inv);
            z.u[1] = pk2bf(o1[j].z * inv, o1[j].w * inv);
            *(short4v*)&ap[16 + lg * 4] = z.v;
        }
    }
}

// ---------------------------------------------------------------------------
// Kernel 3: proj MFMA conv + bias + residual (fp32 out).
// ---------------------------------------------------------------------------
__global__ __launch_bounds__(256) void proj_kernel(
        const short* __restrict__ aoT, const float* __restrict__ pw,
        const float* __restrict__ pb, const float* __restrict__ x,
        float* __restrict__ out) {
    int t = threadIdx.x;
    int n0g = blockIdx.x * 64;
    int b = n0g >> 12, n0 = n0g & (NN - 1);
    int o0 = blockIdx.y * 64;
    int wo = t >> 6, lane = t & 63;
    int lg = lane >> 4, ln = lane & 15;
    int ow = o0 + wo * 16;
    const float* wp = pw + (size_t)(ow + ln) * CC;
    const short* ap = aoT + (size_t)n0g * CC + lg * 8;
    float4v a0 = {0,0,0,0}, a1 = {0,0,0,0}, a2 = {0,0,0,0}, a3 = {0,0,0,0};
    #pragma unroll
    for (int cs = 0; cs < 4; ++cs) {
        float4 wa = *(const float4*)(wp + cs * 32 + lg * 8);
        float4 wb = *(const float4*)(wp + cs * 32 + lg * 8 + 4);
        union { short8 v; unsigned u[4]; } af;
        af.u[0] = pk2bf(wa.x, wa.y); af.u[1] = pk2bf(wa.z, wa.w);
        af.u[2] = pk2bf(wb.x, wb.y); af.u[3] = pk2bf(wb.z, wb.w);
        const short* hp = ap + cs * 32;
        a0 = __builtin_amdgcn_mfma_f32_16x16x32_bf16(af.v, *(const short8*)&hp[(size_t)(0  + ln) * CC], a0, 0, 0, 0);
        a1 = __builtin_amdgcn_mfma_f32_16x16x32_bf16(af.v, *(const short8*)&hp[(size_t)(16 + ln) * CC], a1, 0, 0, 0);
        a2 = __builtin_amdgcn_mfma_f32_16x16x32_bf16(af.v, *(const short8*)&hp[(size_t)(32 + ln) * CC], a2, 0, 0, 0);
        a3 = __builtin_amdgcn_mfma_f32_16x16x32_bf16(af.v, *(const short8*)&hp[(size_t)(48 + ln) * CC], a3, 0, 0, 0);
    }
    int r0 = ow + lg * 4;
    float b0 = pb[r0], b1 = pb[r0 + 1], b2 = pb[r0 + 2], b3 = pb[r0 + 3];
    const float* xbase = x   + ((size_t)b * CC + r0) * NN + n0 + ln;
    float*       obase = out + ((size_t)b * CC + r0) * NN + n0 + ln;
    float4v* accs[4] = {&a0, &a1, &a2, &a3};
    #pragma unroll
    for (int nsub = 0; nsub < 4; ++nsub) {
        float4v av = *accs[nsub];
        const float* xp = xbase + nsub * 16;
        float* op = obase + nsub * 16;
        op[(size_t)0 * NN] = av.x + b0 + xp[(size_t)0 * NN];
        op[(size_t)1 * NN] = av.y + b1 + xp[(size_t)1 * NN];
        op[(size_t)2 * NN] = av.z + b2 + xp[(size_t)2 * NN];
        op[(size_t)3 * NN] = av.w + b3 + xp[(size_t)3 * NN];
    }
}

// ---------------------------------------------------------------------------
extern "C" void kernel_launch(void* const* d_in, const int* in_sizes, int n_in,
                              void* d_out, int out_size, void* d_ws, size_t ws_size,
                              hipStream_t stream) {
    const float* x    = (const float*)d_in[0];
    const float* nw   = (const float*)d_in[1];
    const float* nb   = (const float*)d_in[2];
    const float* qkvw = (const float*)d_in[3];
    const float* qkvb = (const float*)d_in[4];
    const float* pw   = (const float*)d_in[5];
    const float* pb   = (const float*)d_in[6];
    float* out = (float*)d_out;

    // ws (shorts): qT | kT | v | aoT  (4 MB each, 16 MB total)
    short* qT  = (short*)d_ws;
    short* kT  = qT + (size_t)BB * NH * NN * DH;
    short* vv  = kT + (size_t)BB * NH * NN * DH;
    short* aoT = vv + (size_t)BB * NH * DH * NN;

    lnqkv_kernel<<<dim3(256), 512, 0, stream>>>(x, nw, nb, qkvw, qkvb, qT, kT, vv);
    flash_kernel<<<dim3(512), 512, 0, stream>>>(qT, kT, vv, aoT);
    proj_kernel<<<dim3(256, 2), 256, 0, stream>>>(aoT, pw, pb, x, out);
}